// Round 2
// baseline (137.505 us; speedup 1.0000x reference)
//
#include <hip/hip_runtime.h>
#include <hip/hip_bf16.h>

typedef __bf16 bf16_t;
typedef __attribute__((ext_vector_type(8))) __bf16 bf16x8;
typedef __attribute__((ext_vector_type(4))) float f32x4;

#define SEQ    2048
#define DMODEL 1024
#define DPROJ  256
#define NBATCH 4

__device__ __forceinline__ bf16x8 cvt8(const float4& lo, const float4& hi) {
    bf16x8 v;
    v[0] = (bf16_t)lo.x; v[1] = (bf16_t)lo.y; v[2] = (bf16_t)lo.z; v[3] = (bf16_t)lo.w;
    v[4] = (bf16_t)hi.x; v[5] = (bf16_t)hi.y; v[6] = (bf16_t)hi.z; v[7] = (bf16_t)hi.w;
    return v;
}

// ---------------------------------------------------------------------------
// Kernel 1 v2: H[m,p] = relu(sum_d X[m,d]*W[p,d] + b[p]).
// CHANGE vs R1: kill the per-kt vmcnt(0) barrier drain.
//   - __syncthreads() forces hipcc to emit s_waitcnt vmcnt(0) before
//     s_barrier, draining the "distance-2" global prefetch ~0.5 kt after
//     issue -> every kt paid full HBM/L2 latency (latency-serialized,
//     ~1700 cy/kt for ~150 cy of work).
//   - Now: double-buffered LDS (32 KB) + ONE raw barrier per kt:
//     s_waitcnt lgkmcnt(0) (ds ordering only) + __builtin_amdgcn_s_barrier().
//     Global f32x4 prefetch loads issued at top of body cross the barrier
//     un-drained; compiler inserts counted vmcnt only at the cvt8/ds_write
//     consuming them, one full iteration later.
// Schedule per kt: [lgkm0+barrier] [issue loads kt+2 -> xr[kt&1]]
//                  [ds_read+8 MFMA on LDS[kt&1]] [ds_write LDS[kt&1^1] <- kt+1]
// Hazard check: LDS[cur^1] was read during kt-1; all reads complete before
// barrier(kt) (lgkmcnt(0) covers them), so the tail ds_write is safe.
// ---------------------------------------------------------------------------
__global__ __launch_bounds__(256) void proj_kernel(
    const float* __restrict__ X, const float* __restrict__ W,
    const float* __restrict__ bias, bf16_t* __restrict__ H)
{
    __shared__ __align__(16) bf16_t Xs[2][64 * 64];
    __shared__ __align__(16) bf16_t Ws[2][64 * 64];

    const int m0 = blockIdx.x * 64;
    const int n0 = blockIdx.y * 64;
    const int tid  = threadIdx.x;
    const int lane = tid & 63;
    const int wave = tid >> 6;
    const int quad = lane >> 4;
    const int l16  = lane & 15;
    const int wm = (wave & 1) * 32;
    const int wn = (wave >> 1) * 32;
    const int swz = l16 & 7;

    int srow[2], scol[2], soff[2];
    #pragma unroll
    for (int r = 0; r < 2; ++r) {
        const int p = r * 256 + tid;
        srow[r] = p >> 3;
        scol[r] = p & 7;
        soff[r] = srow[r] * 64 + ((scol[r] ^ (srow[r] & 7)) * 8);
    }

    float4 xr[2][2][2], wr[2][2][2];   // [stage][r][half]

    // prologue: load kt=0 and kt=1 into regs
    #pragma unroll
    for (int s = 0; s < 2; ++s) {
        const int k0 = s * 64;
        #pragma unroll
        for (int r = 0; r < 2; ++r) {
            const float* gx = X + (size_t)(m0 + srow[r]) * DMODEL + k0 + scol[r] * 8;
            xr[s][r][0] = *(const float4*)gx;
            xr[s][r][1] = *(const float4*)(gx + 4);
            const float* gw = W + (size_t)(n0 + srow[r]) * DMODEL + k0 + scol[r] * 8;
            wr[s][r][0] = *(const float4*)gw;
            wr[s][r][1] = *(const float4*)(gw + 4);
        }
    }
    // write LDS[0] <- kt=0 data
    #pragma unroll
    for (int r = 0; r < 2; ++r) {
        *(bf16x8*)&Xs[0][soff[r]] = cvt8(xr[0][r][0], xr[0][r][1]);
        *(bf16x8*)&Ws[0][soff[r]] = cvt8(wr[0][r][0], wr[0][r][1]);
    }

    f32x4 acc[2][2] = {};

    #pragma unroll
    for (int kt = 0; kt < 16; ++kt) {
        const int cur = kt & 1;

        // raw barrier: ds ops ordered (lgkm only), vmem prefetch stays in flight
        asm volatile("s_waitcnt lgkmcnt(0)" ::: "memory");
        __builtin_amdgcn_s_barrier();

        // issue global prefetch for kt+2 (consumed by ds_write at kt+1)
        if (kt < 14) {
            const int k0 = (kt + 2) * 64;
            #pragma unroll
            for (int r = 0; r < 2; ++r) {
                const float* gx = X + (size_t)(m0 + srow[r]) * DMODEL + k0 + scol[r] * 8;
                xr[cur][r][0] = *(const float4*)gx;
                xr[cur][r][1] = *(const float4*)(gx + 4);
                const float* gw = W + (size_t)(n0 + srow[r]) * DMODEL + k0 + scol[r] * 8;
                wr[cur][r][0] = *(const float4*)gw;
                wr[cur][r][1] = *(const float4*)(gw + 4);
            }
        }

        // compute on LDS[cur] (kt data)
        #pragma unroll
        for (int ks = 0; ks < 2; ++ks) {
            bf16x8 af[2], bfr[2];
            #pragma unroll
            for (int i = 0; i < 2; ++i) {
                const int ch = (((ks << 2) | quad) ^ swz) * 8;
                af[i]  = *(const bf16x8*)&Xs[cur][(wm + i * 16 + l16) * 64 + ch];
                bfr[i] = *(const bf16x8*)&Ws[cur][(wn + i * 16 + l16) * 64 + ch];
            }
            #pragma unroll
            for (int i = 0; i < 2; ++i)
                #pragma unroll
                for (int j = 0; j < 2; ++j)
                    acc[i][j] = __builtin_amdgcn_mfma_f32_16x16x32_bf16(
                        af[i], bfr[j], acc[i][j], 0, 0, 0);
        }

        // stage kt+1 data into LDS[cur^1] (regs loaded at kt-1; counted vmcnt)
        if (kt < 15) {
            const int s1 = (kt + 1) & 1;
            #pragma unroll
            for (int r = 0; r < 2; ++r) {
                *(bf16x8*)&Xs[cur ^ 1][soff[r]] = cvt8(xr[s1][r][0], xr[s1][r][1]);
                *(bf16x8*)&Ws[cur ^ 1][soff[r]] = cvt8(wr[s1][r][0], wr[s1][r][1]);
            }
        }
    }

    #pragma unroll
    for (int i = 0; i < 2; ++i) {
        #pragma unroll
        for (int j = 0; j < 2; ++j) {
            const int gn = n0 + wn + j * 16 + l16;
            const float bv = bias[gn];
            #pragma unroll
            for (int r = 0; r < 4; ++r) {
                const int gm = m0 + wm + i * 16 + quad * 4 + r;
                float v = acc[i][j][r] + bv;
                v = v > 0.f ? v : 0.f;
                H[(size_t)gm * DPROJ + gn] = (bf16_t)v;
            }
        }
    }
}

// ---------------------------------------------------------------------------
// Kernel 2 v2 (UNCHANGED from R1 — isolate the proj change):
// LDS-free, barrier-free, direct-from-L2 fragment GEMM.
// 128x128 triangular tiles (136/batch, 544 blocks), 4 waves/block,
// each wave a 64x64 quadrant (4x4 frags), full K=256 unrolled.
// ---------------------------------------------------------------------------
__global__ __launch_bounds__(256, 2) void score_kernel(
    const bf16_t* __restrict__ H, const float* __restrict__ clf_w,
    const float* __restrict__ clf_b, float* __restrict__ Out)
{
    // triangular decode: blockIdx.x in [0,136) -> (bi,bj), bi<=bj, T=16
    int t = blockIdx.x, bi = 0, rl = SEQ / 128;
    while (t >= rl) { t -= rl; --rl; ++bi; }
    const int bj = bi + t;
    const int b  = blockIdx.y;
    const int m0 = bi * 128;
    const int n0 = bj * 128;
    const bf16_t* Hb = H + (size_t)b * SEQ * DPROJ;
    float* Ob = Out + (size_t)b * SEQ * SEQ;

    const int tid  = threadIdx.x;
    const int lane = tid & 63;
    const int wave = tid >> 6;
    const int quad = lane >> 4;
    const int l16  = lane & 15;
    const int wm = (wave & 1) * 64;    // 2x2 wave grid, 64x64 per wave
    const int wn = (wave >> 1) * 64;

    // per-lane fragment base pointers (16B-aligned: row*512B + quad*16B)
    const bf16_t* pa = Hb + (size_t)(m0 + wm + l16) * DPROJ + quad * 8;
    const bf16_t* pb = Hb + (size_t)(n0 + wn + l16) * DPROJ + quad * 8;

    f32x4 acc[4][4] = {};

    #pragma unroll
    for (int ks = 0; ks < 8; ++ks) {
        bf16x8 af[4], bfr[4];
        #pragma unroll
        for (int i = 0; i < 4; ++i) {
            af[i]  = *(const bf16x8*)(pa + (size_t)(i * 16) * DPROJ + ks * 32);
            bfr[i] = *(const bf16x8*)(pb + (size_t)(i * 16) * DPROJ + ks * 32);
        }
        #pragma unroll
        for (int i = 0; i < 4; ++i)
            #pragma unroll
            for (int j = 0; j < 4; ++j)
                acc[i][j] = __builtin_amdgcn_mfma_f32_16x16x32_bf16(
                    af[i], bfr[j], acc[i][j], 0, 0, 0);
    }

    const float scale = clf_w[0];
    const float off   = clf_b[0];

    // direct tile (bi,bj): per instr 4 rows (quad) x 16 consecutive cols (l16)
    #pragma unroll
    for (int i = 0; i < 4; ++i) {
        #pragma unroll
        for (int r = 0; r < 4; ++r) {
            const int gm = m0 + wm + i * 16 + quad * 4 + r;
            float* row = Ob + (size_t)gm * SEQ + n0 + wn + l16;
            #pragma unroll
            for (int j = 0; j < 4; ++j)
                row[j * 16] = acc[i][j][r] * scale + off;
        }
    }

    // mirror tile (bj,bi): row gn, 4 consecutive cols gm -> float4 store
    if (bi != bj) {
        #pragma unroll
        for (int j = 0; j < 4; ++j) {
            const int gn = n0 + wn + j * 16 + l16;
            float* row = Ob + (size_t)gn * SEQ + m0 + wm + quad * 4;
            #pragma unroll
            for (int i = 0; i < 4; ++i) {
                float4 v;
                v.x = acc[i][j][0] * scale + off;
                v.y = acc[i][j][1] * scale + off;
                v.z = acc[i][j][2] * scale + off;
                v.w = acc[i][j][3] * scale + off;
                *(float4*)(row + i * 16) = v;
            }
        }
    }
}

extern "C" void kernel_launch(void* const* d_in, const int* in_sizes, int n_in,
                              void* d_out, int out_size, void* d_ws, size_t ws_size,
                              hipStream_t stream) {
    const float* X    = (const float*)d_in[0];  // [4,2048,1024]
    const float* W    = (const float*)d_in[1];  // [256,1024]
    const float* bias = (const float*)d_in[2];  // [256]
    const float* clfw = (const float*)d_in[3];  // [1,1]
    const float* clfb = (const float*)d_in[4];  // [1]
    float* Out = (float*)d_out;                 // [4,2048,2048]
    bf16_t* H  = (bf16_t*)d_ws;                 // [8192,256] bf16 = 4 MB

    dim3 g1(NBATCH * SEQ / 64, DPROJ / 64, 1);  // 128 x 4 = 512 blocks
    proj_kernel<<<g1, 256, 0, stream>>>(X, W, bias, H);

    const int ntile = SEQ / 128;                // 16
    dim3 g2(ntile * (ntile + 1) / 2, NBATCH);   // 136 x 4 = 544 blocks
    score_kernel<<<g2, 256, 0, stream>>>(H, clfw, clfb, Out);
}

// Round 4
// 130.494 us; speedup vs baseline: 1.0537x; 1.0537x over previous
//
#include <hip/hip_runtime.h>
#include <hip/hip_bf16.h>

typedef __bf16 bf16_t;
typedef __attribute__((ext_vector_type(8))) __bf16 bf16x8;
typedef __attribute__((ext_vector_type(4))) float f32x4;

#define SEQ    2048
#define DMODEL 1024
#define DPROJ  256
#define NBATCH 4

__device__ __forceinline__ bf16x8 cvt8(const float4& lo, const float4& hi) {
    bf16x8 v;
    v[0] = (bf16_t)lo.x; v[1] = (bf16_t)lo.y; v[2] = (bf16_t)lo.z; v[3] = (bf16_t)lo.w;
    v[4] = (bf16_t)hi.x; v[5] = (bf16_t)hi.y; v[6] = (bf16_t)hi.z; v[7] = (bf16_t)hi.w;
    return v;
}

// async global->LDS, 16 bytes per lane. LDS dest = wave-uniform base + lane*16.
__device__ __forceinline__ void gl_lds16(const void* g, void* l) {
    __builtin_amdgcn_global_load_lds(
        (const __attribute__((address_space(1))) unsigned int*)g,
        (__attribute__((address_space(3))) unsigned int*)l, 16, 0, 0);
}

// ---------------------------------------------------------------------------
// Kernel 1 v3: H[m,p] = relu(sum_d X[m,d]*W[p,d] + b[p]).
// R0 template EXACTLY (double __syncthreads per K-tile, single-buffer LDS,
// distance-2 VGPR prefetch) — the R2/R3 raw-barrier variant raced (separate
// asm-wait + s_barrier lets the compiler hoist ds_reads over the barrier)
// AND was ~6us slower; reverted to the safe structure.
// Parameter changes only (inherit template correctness):
//   - BK 64 -> 128: 8 K-tiles instead of 16 -> HALF the vmcnt(0) barrier
//     drains (the per-kt ~900cy exposed-latency events), 2x MFMA per phase.
//     LDS = 2 x 64x128 bf16 = 32 KB (grid-limited 2 blocks/CU regardless).
//   - 1D grid, N-fast decode: 4 blocks sharing an X-tile dispatch adjacently
//     (co-resident across XCDs -> X served from L3/L2, not HBM re-fetch).
// Swizzle: 16 chunks/row, stored at chunk^(row&7) (low-3-bit XOR), read at
// ((ks<<2)|quad)^swz — 2-way bank aliasing on reads (free, m136).
// ---------------------------------------------------------------------------
__global__ __launch_bounds__(256) void proj_kernel(
    const float* __restrict__ X, const float* __restrict__ W,
    const float* __restrict__ bias, bf16_t* __restrict__ H)
{
    __shared__ __align__(16) bf16_t Xs[64 * 128];   // 16 KB
    __shared__ __align__(16) bf16_t Ws[64 * 128];   // 16 KB

    const int m0 = (blockIdx.x >> 2) * 64;          // M-tile (128 of them)
    const int n0 = (blockIdx.x & 3) * 64;           // N-tile fast -> L3 reuse
    const int tid  = threadIdx.x;
    const int lane = tid & 63;
    const int wave = tid >> 6;
    const int quad = lane >> 4;
    const int l16  = lane & 15;
    const int wm = (wave & 1) * 32;
    const int wn = (wave >> 1) * 32;
    const int swz = l16 & 7;

    // staging decomposition: 1024 chunks (8 bf16 each) per matrix per K-tile,
    // 4 per thread: p = r*256+tid, row = p>>4, logical chunk col = p&15,
    // stored at col^(row&7) (XOR touches low 3 bits only).
    int srow[4], scol[4], soff[4];
    #pragma unroll
    for (int r = 0; r < 4; ++r) {
        const int p = r * 256 + tid;
        srow[r] = p >> 4;
        scol[r] = p & 15;
        soff[r] = srow[r] * 128 + ((scol[r] ^ (srow[r] & 7)) * 8);
    }

    float4 xr[2][4][2], wr[2][4][2];   // [stage][r][half]  (128 VGPR)

    // prologue: preload kt=0 and kt=1 (distance-2)
    #pragma unroll
    for (int s = 0; s < 2; ++s) {
        const int k0 = s * 128;
        #pragma unroll
        for (int r = 0; r < 4; ++r) {
            const float* gx = X + (size_t)(m0 + srow[r]) * DMODEL + k0 + scol[r] * 8;
            xr[s][r][0] = *(const float4*)gx;
            xr[s][r][1] = *(const float4*)(gx + 4);
            const float* gw = W + (size_t)(n0 + srow[r]) * DMODEL + k0 + scol[r] * 8;
            wr[s][r][0] = *(const float4*)gw;
            wr[s][r][1] = *(const float4*)(gw + 4);
        }
    }

    f32x4 acc[2][2] = {};

    #pragma unroll
    for (int kt = 0; kt < 8; ++kt) {
        const int s = kt & 1;
        __syncthreads();
        #pragma unroll
        for (int r = 0; r < 4; ++r) {
            *(bf16x8*)&Xs[soff[r]] = cvt8(xr[s][r][0], xr[s][r][1]);
            *(bf16x8*)&Ws[soff[r]] = cvt8(wr[s][r][0], wr[s][r][1]);
        }
        __syncthreads();

        if (kt < 6) {
            const int k0 = (kt + 2) * 128;
            #pragma unroll
            for (int r = 0; r < 4; ++r) {
                const float* gx = X + (size_t)(m0 + srow[r]) * DMODEL + k0 + scol[r] * 8;
                xr[s][r][0] = *(const float4*)gx;
                xr[s][r][1] = *(const float4*)(gx + 4);
                const float* gw = W + (size_t)(n0 + srow[r]) * DMODEL + k0 + scol[r] * 8;
                wr[s][r][0] = *(const float4*)gw;
                wr[s][r][1] = *(const float4*)(gw + 4);
            }
        }

        #pragma unroll
        for (int ks = 0; ks < 4; ++ks) {
            bf16x8 af[2], bfr[2];
            const int ch = (((ks << 2) | quad) ^ swz) * 8;
            #pragma unroll
            for (int i = 0; i < 2; ++i) {
                af[i]  = *(const bf16x8*)&Xs[(wm + i * 16 + l16) * 128 + ch];
                bfr[i] = *(const bf16x8*)&Ws[(wn + i * 16 + l16) * 128 + ch];
            }
            #pragma unroll
            for (int i = 0; i < 2; ++i)
                #pragma unroll
                for (int j = 0; j < 2; ++j)
                    acc[i][j] = __builtin_amdgcn_mfma_f32_16x16x32_bf16(
                        af[i], bfr[j], acc[i][j], 0, 0, 0);
        }
    }

    #pragma unroll
    for (int i = 0; i < 2; ++i) {
        #pragma unroll
        for (int j = 0; j < 2; ++j) {
            const int gn = n0 + wn + j * 16 + l16;
            const float bv = bias[gn];
            #pragma unroll
            for (int r = 0; r < 4; ++r) {
                const int gm = m0 + wm + i * 16 + quad * 4 + r;
                float v = acc[i][j][r] + bv;
                v = v > 0.f ? v : 0.f;
                H[(size_t)gm * DPROJ + gn] = (bf16_t)v;
            }
        }
    }
}

// ---------------------------------------------------------------------------
// Kernel 2 (R0 known-good, UNTOUCHED): Out[b,i,j] = scale*sum_p H[i,p]H[j,p]+off.
// 64x64 TRIANGULAR tiles: 528/batch, 2112 blocks, 256 thr, 16KB LDS ->
// 8 co-resident blocks/CU. Latency hidden by block TURNOVER (R1's 128^2
// L2-direct variant at 2.1 blocks/CU regressed +10.5us). ~11us vs 10.6us
// floor for the 67 MB Out store stream — at roofline, leave alone.
// ---------------------------------------------------------------------------
__global__ __launch_bounds__(256, 8) void score_kernel(
    const bf16_t* __restrict__ H, const float* __restrict__ clf_w,
    const float* __restrict__ clf_b, float* __restrict__ Out)
{
    __shared__ __align__(16) bf16_t As[64 * 64];   // 8 KB
    __shared__ __align__(16) bf16_t Bs[64 * 64];   // 8 KB

    // triangular decode: blockIdx.x in [0,528) -> (bi,bj), bi<=bj, T=32
    int t = blockIdx.x, bi = 0, rl = SEQ / 64;
    while (t >= rl) { t -= rl; --rl; ++bi; }
    const int bj = bi + t;
    const int b  = blockIdx.y;
    const int m0 = bi * 64;
    const int n0 = bj * 64;
    const bf16_t* Hb = H + (size_t)b * SEQ * DPROJ;
    float* Ob = Out + (size_t)b * SEQ * SEQ;

    const int tid  = threadIdx.x;
    const int lane = tid & 63;
    const int wave = tid >> 6;
    const int quad = lane >> 4;
    const int l16  = lane & 15;
    const int wm = (wave & 1) * 32;
    const int wn = (wave >> 1) * 32;
    const int swz = l16 & 7;

    // staging: 512 16B chunks per matrix per K-tile; instr t2 in {0,1}:
    // g = (wave*2+t2)*64 + lane; row = g>>3, stored chunk = (g&7)^(row&7)
    const bf16_t* gA[2];
    const bf16_t* gB[2];
    bf16_t* lA[2];
    bf16_t* lB[2];
    #pragma unroll
    for (int t2 = 0; t2 < 2; ++t2) {
        const int g   = (wave * 2 + t2) * 64 + lane;
        const int row = g >> 3;
        const int gc  = (g & 7) ^ (row & 7);
        gA[t2] = Hb + (size_t)(m0 + row) * DPROJ + gc * 8;
        gB[t2] = Hb + (size_t)(n0 + row) * DPROJ + gc * 8;
        lA[t2] = As + (wave * 2 + t2) * 512;
        lB[t2] = Bs + (wave * 2 + t2) * 512;
    }

    f32x4 acc[2][2] = {};

    for (int kt = 0; kt < 4; ++kt) {
        __syncthreads();
        #pragma unroll
        for (int t2 = 0; t2 < 2; ++t2) {
            gl_lds16(gA[t2], lA[t2]);
            gl_lds16(gB[t2], lB[t2]);
        }
        __syncthreads();               // drains vmcnt -> data visible
        #pragma unroll
        for (int t2 = 0; t2 < 2; ++t2) { gA[t2] += 64; gB[t2] += 64; }

        #pragma unroll
        for (int ks = 0; ks < 2; ++ks) {
            const int ch = (((ks << 2) | quad) ^ swz) * 8;
            bf16x8 af[2], bfr[2];
            #pragma unroll
            for (int i = 0; i < 2; ++i) {
                af[i]  = *(const bf16x8*)&As[(wm + i * 16 + l16) * 64 + ch];
                bfr[i] = *(const bf16x8*)&Bs[(wn + i * 16 + l16) * 64 + ch];
            }
            #pragma unroll
            for (int i = 0; i < 2; ++i)
                #pragma unroll
                for (int j = 0; j < 2; ++j)
                    acc[i][j] = __builtin_amdgcn_mfma_f32_16x16x32_bf16(
                        af[i], bfr[j], acc[i][j], 0, 0, 0);
        }
    }

    const float scale = clf_w[0];
    const float off   = clf_b[0];

    // direct tile (bi,bj)
    #pragma unroll
    for (int i = 0; i < 2; ++i)
        #pragma unroll
        for (int j = 0; j < 2; ++j)
            #pragma unroll
            for (int r = 0; r < 4; ++r) {
                const int gm = m0 + wm + i * 16 + quad * 4 + r;
                const int gn = n0 + wn + j * 16 + l16;
                Ob[(size_t)gm * SEQ + gn] = acc[i][j][r] * scale + off;
            }

    // mirror tile (bj,bi): row gn, 4 consecutive cols gm -> float4 store
    if (bi != bj) {
        #pragma unroll
        for (int i = 0; i < 2; ++i)
            #pragma unroll
            for (int j = 0; j < 2; ++j) {
                const int gn = n0 + wn + j * 16 + l16;
                const int gm = m0 + wm + i * 16 + quad * 4;
                float4 v;
                v.x = acc[i][j][0] * scale + off;
                v.y = acc[i][j][1] * scale + off;
                v.z = acc[i][j][2] * scale + off;
                v.w = acc[i][j][3] * scale + off;
                *(float4*)&Ob[(size_t)gn * SEQ + gm] = v;
            }
    }
}

extern "C" void kernel_launch(void* const* d_in, const int* in_sizes, int n_in,
                              void* d_out, int out_size, void* d_ws, size_t ws_size,
                              hipStream_t stream) {
    const float* X    = (const float*)d_in[0];  // [4,2048,1024]
    const float* W    = (const float*)d_in[1];  // [256,1024]
    const float* bias = (const float*)d_in[2];  // [256]
    const float* clfw = (const float*)d_in[3];  // [1,1]
    const float* clfb = (const float*)d_in[4];  // [1]
    float* Out = (float*)d_out;                 // [4,2048,2048]
    bf16_t* H  = (bf16_t*)d_ws;                 // [8192,256] bf16 = 4 MB

    dim3 g1(NBATCH * SEQ / 64 * (DPROJ / 64), 1, 1);  // 512 blocks, 1D, N-fast
    proj_kernel<<<g1, 256, 0, stream>>>(X, W, bias, H);

    const int ntile = SEQ / 64;                 // 32
    dim3 g2(ntile * (ntile + 1) / 2, NBATCH);   // 528 x 4 = 2112 blocks
    score_kernel<<<g2, 256, 0, stream>>>(H, clfw, clfb, Out);
}

// Round 5
// 127.882 us; speedup vs baseline: 1.0752x; 1.0204x over previous
//
#include <hip/hip_runtime.h>
#include <hip/hip_bf16.h>

typedef __bf16 bf16_t;
typedef __attribute__((ext_vector_type(8))) __bf16 bf16x8;
typedef __attribute__((ext_vector_type(4))) float f32x4;

#define SEQ    2048
#define DMODEL 1024
#define DPROJ  256
#define NBATCH 4

__device__ __forceinline__ bf16x8 cvt8(const float4& lo, const float4& hi) {
    bf16x8 v;
    v[0] = (bf16_t)lo.x; v[1] = (bf16_t)lo.y; v[2] = (bf16_t)lo.z; v[3] = (bf16_t)lo.w;
    v[4] = (bf16_t)hi.x; v[5] = (bf16_t)hi.y; v[6] = (bf16_t)hi.z; v[7] = (bf16_t)hi.w;
    return v;
}

// async global->LDS, 16 bytes per lane. LDS dest = wave-uniform base + lane*16.
__device__ __forceinline__ void gl_lds16(const void* g, void* l) {
    __builtin_amdgcn_global_load_lds(
        (const __attribute__((address_space(1))) unsigned int*)g,
        (__attribute__((address_space(3))) unsigned int*)l, 16, 0, 0);
}

// ---------------------------------------------------------------------------
// Kernel 1 v4: H[m,p] = relu(sum_d X[m,d]*W[p,d] + b[p]).
// R0 template EXACTLY (double __syncthreads per kt, single-buffer LDS,
// distance-2 VGPR prefetch, 2D grid). ONE parameter change: BN 64 -> 32.
//   Why: proj at 512 blocks = 2 blocks/CU is co-residency-starved — each
//   phase exposes ~600cy of load latency and there is only ONE other block
//   context to cover it (score's 8-per-CU turnover vs R1's 2-per-CU A/B
//   proved this lever on this workload). BN=32 -> 1024 blocks = 4/CU,
//   LDS 12 KB, staging regs 12 float4, __launch_bounds__(256,4) (<=128 VGPR).
//   X-tile sharers (same m0, 8 N-blocks) sit 128 apart in dispatch; 128%8==0
//   -> same XCD -> X served from that XCD's L2 (R4 taught: 1D N-fast grid
//   scattered sharers across XCDs and cost +9us in X re-fetch).
//   W re-reads x8 vs x4, but W = 1 MB -> pure L2 traffic, ~free.
// ---------------------------------------------------------------------------
__global__ __launch_bounds__(256, 4) void proj_kernel(
    const float* __restrict__ X, const float* __restrict__ W,
    const float* __restrict__ bias, bf16_t* __restrict__ H)
{
    __shared__ __align__(16) bf16_t Xs[64 * 64];   // 8 KB
    __shared__ __align__(16) bf16_t Ws[32 * 64];   // 4 KB

    const int m0 = blockIdx.x * 64;
    const int n0 = blockIdx.y * 32;
    const int tid  = threadIdx.x;
    const int lane = tid & 63;
    const int wave = tid >> 6;
    const int quad = lane >> 4;
    const int l16  = lane & 15;
    const int wm = (wave & 1) * 32;     // M-half
    const int wn = (wave >> 1) * 16;    // N-half
    const int swz = l16 & 7;

    // X staging: 512 chunks (8 bf16) / 256 thr = 2 per thread (R0 pattern)
    int srow[2], scol[2], soff[2];
    #pragma unroll
    for (int r = 0; r < 2; ++r) {
        const int p = r * 256 + tid;
        srow[r] = p >> 3;
        scol[r] = p & 7;
        soff[r] = srow[r] * 64 + ((scol[r] ^ (srow[r] & 7)) * 8);
    }
    // W staging: 256 chunks / 256 thr = 1 per thread
    const int wrow = tid >> 3;
    const int wcol = tid & 7;
    const int woff = wrow * 64 + ((wcol ^ (wrow & 7)) * 8);

    float4 xr[2][2][2];   // [stage][r][half]
    float4 wr[2][2];      // [stage][half]

    // prologue: preload kt=0 and kt=1 (distance-2)
    #pragma unroll
    for (int s = 0; s < 2; ++s) {
        const int k0 = s * 64;
        #pragma unroll
        for (int r = 0; r < 2; ++r) {
            const float* gx = X + (size_t)(m0 + srow[r]) * DMODEL + k0 + scol[r] * 8;
            xr[s][r][0] = *(const float4*)gx;
            xr[s][r][1] = *(const float4*)(gx + 4);
        }
        const float* gw = W + (size_t)(n0 + wrow) * DMODEL + k0 + wcol * 8;
        wr[s][0] = *(const float4*)gw;
        wr[s][1] = *(const float4*)(gw + 4);
    }

    f32x4 acc[2] = {};   // [i] : M-frag; single N-frag per wave

    #pragma unroll
    for (int kt = 0; kt < 16; ++kt) {
        const int s = kt & 1;
        __syncthreads();
        #pragma unroll
        for (int r = 0; r < 2; ++r)
            *(bf16x8*)&Xs[soff[r]] = cvt8(xr[s][r][0], xr[s][r][1]);
        *(bf16x8*)&Ws[woff] = cvt8(wr[s][0], wr[s][1]);
        __syncthreads();

        if (kt < 14) {
            const int k0 = (kt + 2) * 64;
            #pragma unroll
            for (int r = 0; r < 2; ++r) {
                const float* gx = X + (size_t)(m0 + srow[r]) * DMODEL + k0 + scol[r] * 8;
                xr[s][r][0] = *(const float4*)gx;
                xr[s][r][1] = *(const float4*)(gx + 4);
            }
            const float* gw = W + (size_t)(n0 + wrow) * DMODEL + k0 + wcol * 8;
            wr[s][0] = *(const float4*)gw;
            wr[s][1] = *(const float4*)(gw + 4);
        }

        #pragma unroll
        for (int ks = 0; ks < 2; ++ks) {
            const int ch = (((ks << 2) | quad) ^ swz) * 8;
            bf16x8 af[2], bf;
            #pragma unroll
            for (int i = 0; i < 2; ++i)
                af[i] = *(const bf16x8*)&Xs[(wm + i * 16 + l16) * 64 + ch];
            bf = *(const bf16x8*)&Ws[(wn + l16) * 64 + ch];
            #pragma unroll
            for (int i = 0; i < 2; ++i)
                acc[i] = __builtin_amdgcn_mfma_f32_16x16x32_bf16(
                    af[i], bf, acc[i], 0, 0, 0);
        }
    }

    {
        const int gn = n0 + wn + l16;
        const float bv = bias[gn];
        #pragma unroll
        for (int i = 0; i < 2; ++i) {
            #pragma unroll
            for (int r = 0; r < 4; ++r) {
                const int gm = m0 + wm + i * 16 + quad * 4 + r;
                float v = acc[i][r] + bv;
                v = v > 0.f ? v : 0.f;
                H[(size_t)gm * DPROJ + gn] = (bf16_t)v;
            }
        }
    }
}

// ---------------------------------------------------------------------------
// Kernel 2 (R0 known-good, UNTOUCHED): Out[b,i,j] = scale*sum_p H[i,p]H[j,p]+off.
// 64x64 TRIANGULAR tiles: 528/batch, 2112 blocks, 256 thr, 16KB LDS ->
// 8 co-resident blocks/CU. Latency hidden by block TURNOVER (R1's 128^2
// L2-direct variant at 2.1 blocks/CU regressed +10.5us). ~11us vs 10.6us
// floor for the 67 MB Out store stream — at roofline, leave alone.
// ---------------------------------------------------------------------------
__global__ __launch_bounds__(256, 8) void score_kernel(
    const bf16_t* __restrict__ H, const float* __restrict__ clf_w,
    const float* __restrict__ clf_b, float* __restrict__ Out)
{
    __shared__ __align__(16) bf16_t As[64 * 64];   // 8 KB
    __shared__ __align__(16) bf16_t Bs[64 * 64];   // 8 KB

    // triangular decode: blockIdx.x in [0,528) -> (bi,bj), bi<=bj, T=32
    int t = blockIdx.x, bi = 0, rl = SEQ / 64;
    while (t >= rl) { t -= rl; --rl; ++bi; }
    const int bj = bi + t;
    const int b  = blockIdx.y;
    const int m0 = bi * 64;
    const int n0 = bj * 64;
    const bf16_t* Hb = H + (size_t)b * SEQ * DPROJ;
    float* Ob = Out + (size_t)b * SEQ * SEQ;

    const int tid  = threadIdx.x;
    const int lane = tid & 63;
    const int wave = tid >> 6;
    const int quad = lane >> 4;
    const int l16  = lane & 15;
    const int wm = (wave & 1) * 32;
    const int wn = (wave >> 1) * 32;
    const int swz = l16 & 7;

    // staging: 512 16B chunks per matrix per K-tile; instr t2 in {0,1}:
    // g = (wave*2+t2)*64 + lane; row = g>>3, stored chunk = (g&7)^(row&7)
    const bf16_t* gA[2];
    const bf16_t* gB[2];
    bf16_t* lA[2];
    bf16_t* lB[2];
    #pragma unroll
    for (int t2 = 0; t2 < 2; ++t2) {
        const int g   = (wave * 2 + t2) * 64 + lane;
        const int row = g >> 3;
        const int gc  = (g & 7) ^ (row & 7);
        gA[t2] = Hb + (size_t)(m0 + row) * DPROJ + gc * 8;
        gB[t2] = Hb + (size_t)(n0 + row) * DPROJ + gc * 8;
        lA[t2] = As + (wave * 2 + t2) * 512;
        lB[t2] = Bs + (wave * 2 + t2) * 512;
    }

    f32x4 acc[2][2] = {};

    for (int kt = 0; kt < 4; ++kt) {
        __syncthreads();
        #pragma unroll
        for (int t2 = 0; t2 < 2; ++t2) {
            gl_lds16(gA[t2], lA[t2]);
            gl_lds16(gB[t2], lB[t2]);
        }
        __syncthreads();               // drains vmcnt -> data visible
        #pragma unroll
        for (int t2 = 0; t2 < 2; ++t2) { gA[t2] += 64; gB[t2] += 64; }

        #pragma unroll
        for (int ks = 0; ks < 2; ++ks) {
            const int ch = (((ks << 2) | quad) ^ swz) * 8;
            bf16x8 af[2], bfr[2];
            #pragma unroll
            for (int i = 0; i < 2; ++i) {
                af[i]  = *(const bf16x8*)&As[(wm + i * 16 + l16) * 64 + ch];
                bfr[i] = *(const bf16x8*)&Bs[(wn + i * 16 + l16) * 64 + ch];
            }
            #pragma unroll
            for (int i = 0; i < 2; ++i)
                #pragma unroll
                for (int j = 0; j < 2; ++j)
                    acc[i][j] = __builtin_amdgcn_mfma_f32_16x16x32_bf16(
                        af[i], bfr[j], acc[i][j], 0, 0, 0);
        }
    }

    const float scale = clf_w[0];
    const float off   = clf_b[0];

    // direct tile (bi,bj)
    #pragma unroll
    for (int i = 0; i < 2; ++i)
        #pragma unroll
        for (int j = 0; j < 2; ++j)
            #pragma unroll
            for (int r = 0; r < 4; ++r) {
                const int gm = m0 + wm + i * 16 + quad * 4 + r;
                const int gn = n0 + wn + j * 16 + l16;
                Ob[(size_t)gm * SEQ + gn] = acc[i][j][r] * scale + off;
            }

    // mirror tile (bj,bi): row gn, 4 consecutive cols gm -> float4 store
    if (bi != bj) {
        #pragma unroll
        for (int i = 0; i < 2; ++i)
            #pragma unroll
            for (int j = 0; j < 2; ++j) {
                const int gn = n0 + wn + j * 16 + l16;
                const int gm = m0 + wm + i * 16 + quad * 4;
                float4 v;
                v.x = acc[i][j][0] * scale + off;
                v.y = acc[i][j][1] * scale + off;
                v.z = acc[i][j][2] * scale + off;
                v.w = acc[i][j][3] * scale + off;
                *(float4*)&Ob[(size_t)gn * SEQ + gm] = v;
            }
    }
}

extern "C" void kernel_launch(void* const* d_in, const int* in_sizes, int n_in,
                              void* d_out, int out_size, void* d_ws, size_t ws_size,
                              hipStream_t stream) {
    const float* X    = (const float*)d_in[0];  // [4,2048,1024]
    const float* W    = (const float*)d_in[1];  // [256,1024]
    const float* bias = (const float*)d_in[2];  // [256]
    const float* clfw = (const float*)d_in[3];  // [1,1]
    const float* clfb = (const float*)d_in[4];  // [1]
    float* Out = (float*)d_out;                 // [4,2048,2048]
    bf16_t* H  = (bf16_t*)d_ws;                 // [8192,256] bf16 = 4 MB

    dim3 g1(NBATCH * SEQ / 64, DPROJ / 32, 1);  // 128 x 8 = 1024 blocks, 4/CU
    proj_kernel<<<g1, 256, 0, stream>>>(X, W, bias, H);

    const int ntile = SEQ / 64;                 // 32
    dim3 g2(ntile * (ntile + 1) / 2, NBATCH);   // 528 x 4 = 2112 blocks
    score_kernel<<<g2, 256, 0, stream>>>(H, clfw, clfb, Out);
}

// Round 7
// 121.654 us; speedup vs baseline: 1.1303x; 1.0512x over previous
//
#include <hip/hip_runtime.h>
#include <hip/hip_bf16.h>

typedef __bf16 bf16_t;
typedef __attribute__((ext_vector_type(8))) __bf16 bf16x8;
typedef __attribute__((ext_vector_type(4))) float f32x4;

#define SEQ    2048
#define DMODEL 1024
#define DPROJ  256
#define NBATCH 4

__device__ __forceinline__ bf16x8 cvt8(const float4& lo, const float4& hi) {
    bf16x8 v;
    v[0] = (bf16_t)lo.x; v[1] = (bf16_t)lo.y; v[2] = (bf16_t)lo.z; v[3] = (bf16_t)lo.w;
    v[4] = (bf16_t)hi.x; v[5] = (bf16_t)hi.y; v[6] = (bf16_t)hi.z; v[7] = (bf16_t)hi.w;
    return v;
}

// async global->LDS, 16 bytes per lane. LDS dest = wave-uniform base + lane*16.
__device__ __forceinline__ void gl_lds16(const void* g, void* l) {
    __builtin_amdgcn_global_load_lds(
        (const __attribute__((address_space(1))) unsigned int*)g,
        (__attribute__((address_space(3))) unsigned int*)l, 16, 0, 0);
}

// ---------------------------------------------------------------------------
// Kernel 1 v5: H[m,p] = relu(sum_d X[m,d]*W[p,d] + b[p]).
// R0 template with ONE change: double-buffered LDS -> ONE __syncthreads per
// kt instead of two (32 -> 16 barrier-drain events; each __syncthreads drains
// vmcnt(0)+lgkmcnt(0) for all 8 waves/CU at once — the dominant stall).
// Memory-model safety with plain __syncthreads only (no asm barriers):
//   buffer s is READ at kt (after barrier(kt)); those ds_reads are lgkm-
//   drained by barrier(kt+1); the next WRITE of buffer s is at kt+2, after
//   the writer passed barrier(kt+1). No wave can overwrite a buffer another
//   wave still reads. (R2's racy variant split asm-wait from s_barrier,
//   letting the compiler hoist ds_reads across — not done here.)
// Everything else byte-identical to R0: staging pattern, swizzle, distance-2
// VGPR prefetch, 2D grid (X-tile sharers 128 apart -> same XCD L2), epilogue.
// Failed variants for the record: raw-barrier dbuf (+6, racy), BK=128+1D
// grid (+9, grid was the culprit), BN=32 4/CU (+6.6, 2x staging per FLOP).
// ---------------------------------------------------------------------------
__global__ __launch_bounds__(256) void proj_kernel(
    const float* __restrict__ X, const float* __restrict__ W,
    const float* __restrict__ bias, bf16_t* __restrict__ H)
{
    __shared__ __align__(16) bf16_t Xs[2][64 * 64];   // 2 x 8 KB
    __shared__ __align__(16) bf16_t Ws[2][64 * 64];   // 2 x 8 KB

    const int m0 = blockIdx.x * 64;
    const int n0 = blockIdx.y * 64;
    const int tid  = threadIdx.x;
    const int lane = tid & 63;
    const int wave = tid >> 6;
    const int quad = lane >> 4;
    const int l16  = lane & 15;
    const int wm = (wave & 1) * 32;
    const int wn = (wave >> 1) * 32;
    const int swz = l16 & 7;

    int srow[2], scol[2], soff[2];
    #pragma unroll
    for (int r = 0; r < 2; ++r) {
        const int p = r * 256 + tid;
        srow[r] = p >> 3;
        scol[r] = p & 7;
        soff[r] = srow[r] * 64 + ((scol[r] ^ (srow[r] & 7)) * 8);
    }

    float4 xr[2][2][2], wr[2][2][2];   // [stage][r][half]

    // prologue: preload kt=0 and kt=1 (distance-2)
    #pragma unroll
    for (int s = 0; s < 2; ++s) {
        const int k0 = s * 64;
        #pragma unroll
        for (int r = 0; r < 2; ++r) {
            const float* gx = X + (size_t)(m0 + srow[r]) * DMODEL + k0 + scol[r] * 8;
            xr[s][r][0] = *(const float4*)gx;
            xr[s][r][1] = *(const float4*)(gx + 4);
            const float* gw = W + (size_t)(n0 + srow[r]) * DMODEL + k0 + scol[r] * 8;
            wr[s][r][0] = *(const float4*)gw;
            wr[s][r][1] = *(const float4*)(gw + 4);
        }
    }

    f32x4 acc[2][2] = {};

    #pragma unroll
    for (int kt = 0; kt < 16; ++kt) {
        const int s = kt & 1;

        // write LDS[s] from regs loaded at kt-2 (or prologue)
        #pragma unroll
        for (int r = 0; r < 2; ++r) {
            *(bf16x8*)&Xs[s][soff[r]] = cvt8(xr[s][r][0], xr[s][r][1]);
            *(bf16x8*)&Ws[s][soff[r]] = cvt8(wr[s][r][0], wr[s][r][1]);
        }
        __syncthreads();   // single barrier per kt: writes visible, reads of
                           // buffer s^1 (kt-1) were drained by this wave's
                           // own lgkmcnt(0) here; buffer s^1 written at kt+1

        // issue global prefetch for kt+2 into xr[s] (regs now free)
        if (kt < 14) {
            const int k0 = (kt + 2) * 64;
            #pragma unroll
            for (int r = 0; r < 2; ++r) {
                const float* gx = X + (size_t)(m0 + srow[r]) * DMODEL + k0 + scol[r] * 8;
                xr[s][r][0] = *(const float4*)gx;
                xr[s][r][1] = *(const float4*)(gx + 4);
                const float* gw = W + (size_t)(n0 + srow[r]) * DMODEL + k0 + scol[r] * 8;
                wr[s][r][0] = *(const float4*)gw;
                wr[s][r][1] = *(const float4*)(gw + 4);
            }
        }

        // compute on LDS[s]
        #pragma unroll
        for (int ks = 0; ks < 2; ++ks) {
            bf16x8 af[2], bfr[2];
            #pragma unroll
            for (int i = 0; i < 2; ++i) {
                const int ch = (((ks << 2) | quad) ^ swz) * 8;
                af[i]  = *(const bf16x8*)&Xs[s][(wm + i * 16 + l16) * 64 + ch];
                bfr[i] = *(const bf16x8*)&Ws[s][(wn + i * 16 + l16) * 64 + ch];
            }
            #pragma unroll
            for (int i = 0; i < 2; ++i)
                #pragma unroll
                for (int j = 0; j < 2; ++j)
                    acc[i][j] = __builtin_amdgcn_mfma_f32_16x16x32_bf16(
                        af[i], bfr[j], acc[i][j], 0, 0, 0);
        }
    }

    #pragma unroll
    for (int i = 0; i < 2; ++i) {
        #pragma unroll
        for (int j = 0; j < 2; ++j) {
            const int gn = n0 + wn + j * 16 + l16;
            const float bv = bias[gn];
            #pragma unroll
            for (int r = 0; r < 4; ++r) {
                const int gm = m0 + wm + i * 16 + quad * 4 + r;
                float v = acc[i][j][r] + bv;
                v = v > 0.f ? v : 0.f;
                H[(size_t)gm * DPROJ + gn] = (bf16_t)v;
            }
        }
    }
}

// ---------------------------------------------------------------------------
// Kernel 2 (R0 known-good, UNTOUCHED): Out[b,i,j] = scale*sum_p H[i,p]H[j,p]+off.
// 64x64 TRIANGULAR tiles: 528/batch, 2112 blocks, 256 thr, 16KB LDS ->
// 8 co-resident blocks/CU. Latency hidden by block TURNOVER (R1's 128^2
// L2-direct variant at 2.1 blocks/CU regressed +10.5us). ~11us vs 10.6us
// floor for the 67 MB Out store stream — at roofline, leave alone.
// ---------------------------------------------------------------------------
__global__ __launch_bounds__(256, 8) void score_kernel(
    const bf16_t* __restrict__ H, const float* __restrict__ clf_w,
    const float* __restrict__ clf_b, float* __restrict__ Out)
{
    __shared__ __align__(16) bf16_t As[64 * 64];   // 8 KB
    __shared__ __align__(16) bf16_t Bs[64 * 64];   // 8 KB

    // triangular decode: blockIdx.x in [0,528) -> (bi,bj), bi<=bj, T=32
    int t = blockIdx.x, bi = 0, rl = SEQ / 64;
    while (t >= rl) { t -= rl; --rl; ++bi; }
    const int bj = bi + t;
    const int b  = blockIdx.y;
    const int m0 = bi * 64;
    const int n0 = bj * 64;
    const bf16_t* Hb = H + (size_t)b * SEQ * DPROJ;
    float* Ob = Out + (size_t)b * SEQ * SEQ;

    const int tid  = threadIdx.x;
    const int lane = tid & 63;
    const int wave = tid >> 6;
    const int quad = lane >> 4;
    const int l16  = lane & 15;
    const int wm = (wave & 1) * 32;
    const int wn = (wave >> 1) * 32;
    const int swz = l16 & 7;

    // staging: 512 16B chunks per matrix per K-tile; instr t2 in {0,1}:
    // g = (wave*2+t2)*64 + lane; row = g>>3, stored chunk = (g&7)^(row&7)
    const bf16_t* gA[2];
    const bf16_t* gB[2];
    bf16_t* lA[2];
    bf16_t* lB[2];
    #pragma unroll
    for (int t2 = 0; t2 < 2; ++t2) {
        const int g   = (wave * 2 + t2) * 64 + lane;
        const int row = g >> 3;
        const int gc  = (g & 7) ^ (row & 7);
        gA[t2] = Hb + (size_t)(m0 + row) * DPROJ + gc * 8;
        gB[t2] = Hb + (size_t)(n0 + row) * DPROJ + gc * 8;
        lA[t2] = As + (wave * 2 + t2) * 512;
        lB[t2] = Bs + (wave * 2 + t2) * 512;
    }

    f32x4 acc[2][2] = {};

    for (int kt = 0; kt < 4; ++kt) {
        __syncthreads();
        #pragma unroll
        for (int t2 = 0; t2 < 2; ++t2) {
            gl_lds16(gA[t2], lA[t2]);
            gl_lds16(gB[t2], lB[t2]);
        }
        __syncthreads();               // drains vmcnt -> data visible
        #pragma unroll
        for (int t2 = 0; t2 < 2; ++t2) { gA[t2] += 64; gB[t2] += 64; }

        #pragma unroll
        for (int ks = 0; ks < 2; ++ks) {
            const int ch = (((ks << 2) | quad) ^ swz) * 8;
            bf16x8 af[2], bfr[2];
            #pragma unroll
            for (int i = 0; i < 2; ++i) {
                af[i]  = *(const bf16x8*)&As[(wm + i * 16 + l16) * 64 + ch];
                bfr[i] = *(const bf16x8*)&Bs[(wn + i * 16 + l16) * 64 + ch];
            }
            #pragma unroll
            for (int i = 0; i < 2; ++i)
                #pragma unroll
                for (int j = 0; j < 2; ++j)
                    acc[i][j] = __builtin_amdgcn_mfma_f32_16x16x32_bf16(
                        af[i], bfr[j], acc[i][j], 0, 0, 0);
        }
    }

    const float scale = clf_w[0];
    const float off   = clf_b[0];

    // direct tile (bi,bj)
    #pragma unroll
    for (int i = 0; i < 2; ++i)
        #pragma unroll
        for (int j = 0; j < 2; ++j)
            #pragma unroll
            for (int r = 0; r < 4; ++r) {
                const int gm = m0 + wm + i * 16 + quad * 4 + r;
                const int gn = n0 + wn + j * 16 + l16;
                Ob[(size_t)gm * SEQ + gn] = acc[i][j][r] * scale + off;
            }

    // mirror tile (bj,bi): row gn, 4 consecutive cols gm -> float4 store
    if (bi != bj) {
        #pragma unroll
        for (int i = 0; i < 2; ++i)
            #pragma unroll
            for (int j = 0; j < 2; ++j) {
                const int gn = n0 + wn + j * 16 + l16;
                const int gm = m0 + wm + i * 16 + quad * 4;
                float4 v;
                v.x = acc[i][j][0] * scale + off;
                v.y = acc[i][j][1] * scale + off;
                v.z = acc[i][j][2] * scale + off;
                v.w = acc[i][j][3] * scale + off;
                *(float4*)&Ob[(size_t)gn * SEQ + gm] = v;
            }
    }
}

extern "C" void kernel_launch(void* const* d_in, const int* in_sizes, int n_in,
                              void* d_out, int out_size, void* d_ws, size_t ws_size,
                              hipStream_t stream) {
    const float* X    = (const float*)d_in[0];  // [4,2048,1024]
    const float* W    = (const float*)d_in[1];  // [256,1024]
    const float* bias = (const float*)d_in[2];  // [256]
    const float* clfw = (const float*)d_in[3];  // [1,1]
    const float* clfb = (const float*)d_in[4];  // [1]
    float* Out = (float*)d_out;                 // [4,2048,2048]
    bf16_t* H  = (bf16_t*)d_ws;                 // [8192,256] bf16 = 4 MB

    dim3 g1(NBATCH * SEQ / 64, DPROJ / 64, 1);  // 128 x 4 = 512 blocks (R0 grid)
    proj_kernel<<<g1, 256, 0, stream>>>(X, W, bias, H);

    const int ntile = SEQ / 64;                 // 32
    dim3 g2(ntile * (ntile + 1) / 2, NBATCH);   // 528 x 4 = 2112 blocks
    score_kernel<<<g2, 256, 0, stream>>>(H, clfw, clfb, Out);
}